// Round 13
// baseline (368.297 us; speedup 1.0000x reference)
//
#include <hip/hip_runtime.h>
#include <math.h>

#define NN 100000
#define NE 1600000
#define DI 256
#define DH 64
#define DO 47
#define DH3 48                      // h3s row stride: 192B -> 19.2 MB footprint
#define NB ((NN + 255) / 256)       // 391 scan blocks
#define RSZ8 ((NN + 7) / 8)         // 12500 nodes per XCD-pinned range
#define EPB 2048                    // edges per fill block
#define CPB ((NE + EPB - 1) / EPB)  // 782 chunks per range

// ---------------- degree, XCD-pinned ranges ----------------
__global__ __launch_bounds__(256) void k_degree(const int* __restrict__ dst,
                                                int* __restrict__ deg) {
    int r = blockIdx.x & 7;
    int chunk = blockIdx.x >> 3;
    int lo = r * RSZ8, hi = min(lo + RSZ8, NN);
    int base = chunk * EPB + threadIdx.x;
    #pragma unroll
    for (int i = 0; i < EPB / 256; ++i) {
        int e = base + i * 256;
        if (e < NE) {
            int d = dst[e];
            if (d >= lo && d < hi) atomicAdd(&deg[d], 1);
        }
    }
}

// ---------------- scan pass 1: per-block sums of deg ----------------
__global__ __launch_bounds__(256) void k_part(const int* __restrict__ deg,
                                              int* __restrict__ part) {
    int i = blockIdx.x * 256 + threadIdx.x;
    int v = (i < NN) ? deg[i] : 0;
    for (int off = 32; off; off >>= 1) v += __shfl_xor(v, off);
    __shared__ int s[4];
    if ((threadIdx.x & 63) == 0) s[threadIdx.x >> 6] = v;
    __syncthreads();
    if (threadIdx.x == 0) part[blockIdx.x] = s[0] + s[1] + s[2] + s[3];
}

// ---------------- scan pass 2: exclusive scan of partials (NB<=512) ----------------
__global__ __launch_bounds__(512) void k_scanpart(int* __restrict__ part) {
    int t = threadIdx.x, lane = t & 63, wv = t >> 6;
    int v0 = (t < NB) ? part[t] : 0;
    int v = v0;
    for (int off = 1; off < 64; off <<= 1) {
        int u = __shfl_up(v, off);
        if (lane >= off) v += u;
    }
    __shared__ int ws[8];
    if (lane == 63) ws[wv] = v;
    __syncthreads();
    if (t == 0) {
        int run = 0;
        for (int w = 0; w < 8; ++w) { int tmp = ws[w]; ws[w] = run; run += tmp; }
    }
    __syncthreads();
    v += ws[wv];
    if (t < NB) part[t] = v - v0;   // exclusive
}

// ---------------- scan pass 3: prefix -> rowptr, cursor; fused dinv ----------------
__global__ __launch_bounds__(256) void k_scan3(const int* __restrict__ deg,
                                               const int* __restrict__ part,
                                               int* __restrict__ rowptr,
                                               int* __restrict__ cursor,
                                               float* __restrict__ dinv) {
    int i = blockIdx.x * 256 + threadIdx.x;
    int lane = threadIdx.x & 63, wv = threadIdx.x >> 6;
    int v0 = (i < NN) ? deg[i] : 0;
    int v = v0;
    for (int off = 1; off < 64; off <<= 1) {
        int u = __shfl_up(v, off);
        if (lane >= off) v += u;
    }
    __shared__ int ws[4], wo[4];
    if (lane == 63) ws[wv] = v;
    __syncthreads();
    if (threadIdx.x == 0) {
        int run = 0;
        for (int w = 0; w < 4; ++w) { int tmp = ws[w]; wo[w] = run; run += tmp; }
    }
    __syncthreads();
    int excl = part[blockIdx.x] + wo[wv] + v - v0;
    if (i < NN) {
        rowptr[i] = excl;
        cursor[i] = excl;
        dinv[i] = rsqrtf((float)(v0 + 1));
    }
}

// ---------------- bucket-fill, XCD-pinned ranges ----------------
__global__ __launch_bounds__(256) void k_fillr(const int* __restrict__ src,
                                               const int* __restrict__ dst,
                                               int* __restrict__ cursor,
                                               int* __restrict__ csr_src) {
    int r = blockIdx.x & 7;
    int chunk = blockIdx.x >> 3;
    int lo = r * RSZ8, hi = min(lo + RSZ8, NN);
    int base = chunk * EPB + threadIdx.x;
    #pragma unroll
    for (int i = 0; i < EPB / 256; ++i) {
        int e = base + i * 256;
        if (e < NE) {
            int d = dst[e];
            if (d >= lo && d < hi) {
                int p = atomicAdd(&cursor[d], 1);
                csr_src[p] = src[e];
            }
        }
    }
}

// ---------------- h1s = dinv * (x @ W1)  (N x 256 x 64), fp32 ----------------
// Pure-DS compute loop (NO SMEM in the k-loop): x tile [2][64*33] + W chunk
// [2][32*64] both in LDS. W read = wave-uniform float4 pair -> broadcast
// ds_read_b128, conflict-free. kk-loop unroll capped at 4 to stop the
// scheduler from deep-pipelining into a VGPR spill (round-11 failure).
__global__ __launch_bounds__(512) void k_gemm1(const float* __restrict__ x,
                                               const float* __restrict__ W1,
                                               const float* __restrict__ dinv,
                                               float* __restrict__ h1s) {
    __shared__ float xs[2][64 * 33];   // 16.9 KB
    __shared__ float wl[2][32 * 64];   // 16 KB
    const int t = threadIdx.x;
    const int lane = t & 63;
    const int wvu = __builtin_amdgcn_readfirstlane(t >> 6);
    const int r0 = blockIdx.x * 64;
    const int sr = t >> 3;             // x staging: 8 threads/row
    const int sk = (t & 7) * 4;        // float4 each
    const int wk = t >> 4;             // W staging: chunk row 0..31
    const int wc = (t & 15) * 4;       // col quad
    const long xrow = (long)min(r0 + sr, NN - 1) * DI;
    const int row = r0 + lane;

    float acc[8] = {0.f, 0.f, 0.f, 0.f, 0.f, 0.f, 0.f, 0.f};

    {   // stage chunk 0 (x + W)
        float4 v = *(const float4*)(x + xrow + sk);
        float* p = &xs[0][sr * 33 + sk];
        p[0] = v.x; p[1] = v.y; p[2] = v.z; p[3] = v.w;
        float4 w = *(const float4*)(W1 + (size_t)wk * DH + wc);
        float* q = &wl[0][wk * 64 + wc];
        q[0] = w.x; q[1] = w.y; q[2] = w.z; q[3] = w.w;
    }
    __syncthreads();
    for (int c = 0; c < 8; ++c) {
        const int buf = c & 1;
        if (c + 1 < 8) {   // stage next chunk into other buffer
            float4 v = *(const float4*)(x + xrow + (c + 1) * 32 + sk);
            float* p = &xs[buf ^ 1][sr * 33 + sk];
            p[0] = v.x; p[1] = v.y; p[2] = v.z; p[3] = v.w;
            float4 w = *(const float4*)(W1 + (size_t)((c + 1) * 32 + wk) * DH + wc);
            float* q = &wl[buf ^ 1][wk * 64 + wc];
            q[0] = w.x; q[1] = w.y; q[2] = w.z; q[3] = w.w;
        }
        #pragma unroll 4
        for (int kk = 0; kk < 32; ++kk) {
            float xv = xs[buf][lane * 33 + kk];
            const float4* wp = (const float4*)&wl[buf][kk * 64 + wvu * 8];
            float4 wa = wp[0], wb = wp[1];
            acc[0] += wa.x * xv; acc[1] += wa.y * xv;
            acc[2] += wa.z * xv; acc[3] += wa.w * xv;
            acc[4] += wb.x * xv; acc[5] += wb.y * xv;
            acc[6] += wb.z * xv; acc[7] += wb.w * xv;
        }
        __syncthreads();
    }
    if (row < NN) {
        float di = dinv[row];
        float4 o0 = {di * acc[0], di * acc[1], di * acc[2], di * acc[3]};
        float4 o1 = {di * acc[4], di * acc[5], di * acc[6], di * acc[7]};
        float4* hp = (float4*)(h1s + (long)row * DH + wvu * 8);
        hp[0] = o0;
        hp[1] = o1;
    }
}

// ---------------- layer1 gather (2 rows/wave) + relu/bias + GEMM2 fused ----------------
__global__ __launch_bounds__(256) void k_agg1(const int* __restrict__ rowptr,
                                              const int* __restrict__ deg,
                                              const int* __restrict__ csr_src,
                                              const float* __restrict__ dinv,
                                              const float* __restrict__ h1s,
                                              const float* __restrict__ b1,
                                              const float* __restrict__ W2,
                                              float* __restrict__ h3s) {
    __shared__ float w2[DH * DO];   // 12 KB
    __shared__ float sh[8][DH];     // 2 KB
    for (int i = threadIdx.x; i < DH * DO; i += 256) w2[i] = W2[i];
    __syncthreads();
    const int wv = threadIdx.x >> 6, lane = threadIdx.x & 63;
    const int rA = blockIdx.x * 8 + wv * 2;
    const int rB = rA + 1;
    const int begA = rowptr[rA], cntA = deg[rA];
    const int begB = rowptr[rB], cntB = deg[rB];
    float accA = 0.f, accB = 0.f;
    const int tmax = max(cntA, cntB);
    #pragma unroll 2
    for (int j = 0; j < tmax; j += 4) {
        #pragma unroll
        for (int k = 0; k < 4; ++k) {
            int sa = csr_src[min(begA + j + k, NE - 1)];
            int sb = csr_src[min(begB + j + k, NE - 1)];
            float va = h1s[(size_t)sa * DH + lane];
            float vb = h1s[(size_t)sb * DH + lane];
            accA += (j + k < cntA) ? va : 0.f;
            accB += (j + k < cntB) ? vb : 0.f;
        }
    }
    const float diA = dinv[rA], diB = dinv[rB];
    float vA = diA * (accA + h1s[(size_t)rA * DH + lane]) + b1[lane];
    float vB = diB * (accB + h1s[(size_t)rB * DH + lane]) + b1[lane];
    sh[wv * 2 + 0][lane] = fmaxf(vA, 0.f);
    sh[wv * 2 + 1][lane] = fmaxf(vB, 0.f);
    __syncthreads();
    if (lane < DO) {
        float oA = 0.f, oB = 0.f;
        #pragma unroll 8
        for (int k = 0; k < DH; ++k) {
            float w = w2[k * DO + lane];
            oA += sh[wv * 2 + 0][k] * w;
            oB += sh[wv * 2 + 1][k] * w;
        }
        h3s[(size_t)rA * DH3 + lane] = diA * oA;
        h3s[(size_t)rB * DH3 + lane] = diB * oB;
    }
}

// ---------------- layer2 gather (2 rows/wave) + softmax/argmax fused ----------------
__global__ __launch_bounds__(256) void k_agg2(const int* __restrict__ rowptr,
                                              const int* __restrict__ deg,
                                              const int* __restrict__ csr_src,
                                              const float* __restrict__ dinv,
                                              const float* __restrict__ h3s,
                                              const float* __restrict__ b2,
                                              float* __restrict__ logits,
                                              float* __restrict__ preds,
                                              float* __restrict__ xo) {
    const int wv = threadIdx.x >> 6, lane = threadIdx.x & 63;
    const int rA = blockIdx.x * 8 + wv * 2;
    const int rB = rA + 1;
    const int begA = rowptr[rA], cntA = deg[rA];
    const int begB = rowptr[rB], cntB = deg[rB];
    const bool act = lane < DO;
    const int lx = act ? lane : 0;
    float accA = 0.f, accB = 0.f;
    const int tmax = max(cntA, cntB);
    #pragma unroll 2
    for (int j = 0; j < tmax; j += 4) {
        #pragma unroll
        for (int k = 0; k < 4; ++k) {
            int sa = csr_src[min(begA + j + k, NE - 1)];
            int sb = csr_src[min(begB + j + k, NE - 1)];
            float va = h3s[(size_t)sa * DH3 + lx];
            float vb = h3s[(size_t)sb * DH3 + lx];
            accA += (j + k < cntA) ? va : 0.f;
            accB += (j + k < cntB) ? vb : 0.f;
        }
    }
    const float diA = dinv[rA], diB = dinv[rB];
    float valA = -INFINITY, valB = -INFINITY;
    if (act) {
        valA = diA * (accA + h3s[(size_t)rA * DH3 + lane]) + b2[lane];
        valB = diB * (accB + h3s[(size_t)rB * DH3 + lane]) + b2[lane];
        xo[(size_t)rA * DO + lane] = valA;
        xo[(size_t)rB * DO + lane] = valB;
    }
    float mA = valA, mB = valB;
    for (int off = 32; off; off >>= 1) {
        mA = fmaxf(mA, __shfl_xor(mA, off));
        mB = fmaxf(mB, __shfl_xor(mB, off));
    }
    int idxA = (act && valA == mA) ? lane : (1 << 30);
    int idxB = (act && valB == mB) ? lane : (1 << 30);
    for (int off = 32; off; off >>= 1) {
        idxA = min(idxA, __shfl_xor(idxA, off));
        idxB = min(idxB, __shfl_xor(idxB, off));
    }
    float evA = act ? expf(valA - mA) : 0.f;
    float evB = act ? expf(valB - mB) : 0.f;
    float sA = evA, sB = evB;
    for (int off = 32; off; off >>= 1) {
        sA += __shfl_xor(sA, off);
        sB += __shfl_xor(sB, off);
    }
    if (act) {
        logits[(size_t)rA * DO + lane] = evA / sA;
        logits[(size_t)rB * DO + lane] = evB / sB;
    }
    if (lane == 0) {
        preds[rA] = (float)idxA;
        preds[rB] = (float)idxB;
    }
}

extern "C" void kernel_launch(void* const* d_in, const int* in_sizes, int n_in,
                              void* d_out, int out_size, void* d_ws, size_t ws_size,
                              hipStream_t stream) {
    const float* x  = (const float*)d_in[0];
    const int*   ei = (const int*)d_in[1];
    const float* W1 = (const float*)d_in[2];
    const float* b1 = (const float*)d_in[3];
    const float* W2 = (const float*)d_in[4];
    const float* b2 = (const float*)d_in[5];
    const int* src = ei;          // edge_index[0]
    const int* dst = ei + NE;     // edge_index[1]

    float* out    = (float*)d_out;
    float* logits = out;                      // [N,47]
    float* preds  = out + (size_t)NN * DO;    // [N]
    float* xo     = preds + NN;               // [N,47]

    // workspace layout (~53 MB)
    char* wsb = (char*)d_ws;
    int*   deg     = (int*)wsb;                         wsb += (size_t)NN * 4;
    float* dinv    = (float*)wsb;                       wsb += (size_t)NN * 4;
    int*   rowptr  = (int*)wsb;                         wsb += (size_t)NN * 4;
    int*   cursor  = (int*)wsb;                         wsb += (size_t)NN * 4;
    int*   part    = (int*)wsb;                         wsb += (size_t)512 * 4;
    int*   csr_src = (int*)wsb;                         wsb += (size_t)NE * 4;
    float* h1s     = (float*)wsb;                       wsb += (size_t)NN * DH * 4;
    float* h3s     = (float*)wsb;                       wsb += (size_t)NN * DH3 * 4;

    hipMemsetAsync(deg, 0, NN * sizeof(int), stream);

    k_degree<<<8 * CPB, 256, 0, stream>>>(dst, deg);
    k_part<<<NB, 256, 0, stream>>>(deg, part);
    k_scanpart<<<1, 512, 0, stream>>>(part);
    k_scan3<<<NB, 256, 0, stream>>>(deg, part, rowptr, cursor, dinv);
    k_fillr<<<8 * CPB, 256, 0, stream>>>(src, dst, cursor, csr_src);
    k_gemm1<<<(NN + 63) / 64, 512, 0, stream>>>(x, W1, dinv, h1s);
    k_agg1<<<NN / 8, 256, 0, stream>>>(rowptr, deg, csr_src, dinv, h1s, b1, W2, h3s);
    k_agg2<<<NN / 8, 256, 0, stream>>>(rowptr, deg, csr_src, dinv, h3s, b2, logits, preds, xo);
}

// Round 14
// 350.135 us; speedup vs baseline: 1.0519x; 1.0519x over previous
//
#include <hip/hip_runtime.h>
#include <math.h>

#define NN 100000
#define NE 1600000
#define DI 256
#define DH 64
#define DO 47
#define DH3 48                      // h3s row stride: 192B -> 19.2 MB footprint
#define NB ((NN + 255) / 256)       // 391 scan blocks
#define RSZ8 ((NN + 7) / 8)         // 12500 nodes per XCD-pinned range
#define EPB 2048                    // edges per fill block
#define CPB ((NE + EPB - 1) / EPB)  // 782 chunks per range

// ---------------- degree, XCD-pinned ranges ----------------
__global__ __launch_bounds__(256) void k_degree(const int* __restrict__ dst,
                                                int* __restrict__ deg) {
    int r = blockIdx.x & 7;
    int chunk = blockIdx.x >> 3;
    int lo = r * RSZ8, hi = min(lo + RSZ8, NN);
    int base = chunk * EPB + threadIdx.x;
    #pragma unroll
    for (int i = 0; i < EPB / 256; ++i) {
        int e = base + i * 256;
        if (e < NE) {
            int d = dst[e];
            if (d >= lo && d < hi) atomicAdd(&deg[d], 1);
        }
    }
}

// ---------------- scan pass 1: per-block sums of deg ----------------
__global__ __launch_bounds__(256) void k_part(const int* __restrict__ deg,
                                              int* __restrict__ part) {
    int i = blockIdx.x * 256 + threadIdx.x;
    int v = (i < NN) ? deg[i] : 0;
    for (int off = 32; off; off >>= 1) v += __shfl_xor(v, off);
    __shared__ int s[4];
    if ((threadIdx.x & 63) == 0) s[threadIdx.x >> 6] = v;
    __syncthreads();
    if (threadIdx.x == 0) part[blockIdx.x] = s[0] + s[1] + s[2] + s[3];
}

// ---------------- scan pass 2: exclusive scan of partials (NB<=512) ----------------
__global__ __launch_bounds__(512) void k_scanpart(int* __restrict__ part) {
    int t = threadIdx.x, lane = t & 63, wv = t >> 6;
    int v0 = (t < NB) ? part[t] : 0;
    int v = v0;
    for (int off = 1; off < 64; off <<= 1) {
        int u = __shfl_up(v, off);
        if (lane >= off) v += u;
    }
    __shared__ int ws[8];
    if (lane == 63) ws[wv] = v;
    __syncthreads();
    if (t == 0) {
        int run = 0;
        for (int w = 0; w < 8; ++w) { int tmp = ws[w]; ws[w] = run; run += tmp; }
    }
    __syncthreads();
    v += ws[wv];
    if (t < NB) part[t] = v - v0;   // exclusive
}

// ---------------- scan pass 3: prefix -> rowptr, cursor; fused dinv ----------------
__global__ __launch_bounds__(256) void k_scan3(const int* __restrict__ deg,
                                               const int* __restrict__ part,
                                               int* __restrict__ rowptr,
                                               int* __restrict__ cursor,
                                               float* __restrict__ dinv) {
    int i = blockIdx.x * 256 + threadIdx.x;
    int lane = threadIdx.x & 63, wv = threadIdx.x >> 6;
    int v0 = (i < NN) ? deg[i] : 0;
    int v = v0;
    for (int off = 1; off < 64; off <<= 1) {
        int u = __shfl_up(v, off);
        if (lane >= off) v += u;
    }
    __shared__ int ws[4], wo[4];
    if (lane == 63) ws[wv] = v;
    __syncthreads();
    if (threadIdx.x == 0) {
        int run = 0;
        for (int w = 0; w < 4; ++w) { int tmp = ws[w]; wo[w] = run; run += tmp; }
    }
    __syncthreads();
    int excl = part[blockIdx.x] + wo[wv] + v - v0;
    if (i < NN) {
        rowptr[i] = excl;
        cursor[i] = excl;
        dinv[i] = rsqrtf((float)(v0 + 1));
    }
}

// ---------------- bucket-fill, XCD-pinned ranges ----------------
__global__ __launch_bounds__(256) void k_fillr(const int* __restrict__ src,
                                               const int* __restrict__ dst,
                                               int* __restrict__ cursor,
                                               int* __restrict__ csr_src) {
    int r = blockIdx.x & 7;
    int chunk = blockIdx.x >> 3;
    int lo = r * RSZ8, hi = min(lo + RSZ8, NN);
    int base = chunk * EPB + threadIdx.x;
    #pragma unroll
    for (int i = 0; i < EPB / 256; ++i) {
        int e = base + i * 256;
        if (e < NE) {
            int d = dst[e];
            if (d >= lo && d < hi) {
                int p = atomicAdd(&cursor[d], 1);
                csr_src[p] = src[e];
            }
        }
    }
}

// ---------------- h1s = dinv * (x @ W1)  (N x 256 x 64), fp32 ----------------
// Register-blocked 2 rows/lane: 128 rows/block, lane owns rows {l, l+64},
// wave owns 8 cols. Each W broadcast (b128, 8clk RF-return) now feeds 16 FMA
// instead of 8 -> LDS return BW no longer the ceiling (r13 post-mortem).
// Pure-DS loop, unroll capped at 4 (r11 spill lesson).
__global__ __launch_bounds__(512) void k_gemm1(const float* __restrict__ x,
                                               const float* __restrict__ W1,
                                               const float* __restrict__ dinv,
                                               float* __restrict__ h1s) {
    __shared__ float xs[2][128 * 33];  // 33.8 KB
    __shared__ float wl[2][32 * 64];   // 16 KB   -> 50 KB total, 3 blocks/CU
    const int t = threadIdx.x;
    const int lane = t & 63;
    const int wvu = __builtin_amdgcn_readfirstlane(t >> 6);
    const int r0 = blockIdx.x * 128;
    const int sr = t >> 2;             // x staging: 4 threads/row (0..127)
    const int sk = (t & 3) * 8;        // 2 float4 at sk, sk+4
    const int wk = t >> 4;             // W staging: chunk row 0..31
    const int wc = (t & 15) * 4;       // col quad
    const long xrow = (long)min(r0 + sr, NN - 1) * DI;
    const int rowA = r0 + lane;
    const int rowB = r0 + 64 + lane;

    float accA[8] = {0.f, 0.f, 0.f, 0.f, 0.f, 0.f, 0.f, 0.f};
    float accB[8] = {0.f, 0.f, 0.f, 0.f, 0.f, 0.f, 0.f, 0.f};

    {   // stage chunk 0 (x + W)
        float4 v0 = *(const float4*)(x + xrow + sk);
        float4 v1 = *(const float4*)(x + xrow + sk + 4);
        float* p = &xs[0][sr * 33 + sk];
        p[0] = v0.x; p[1] = v0.y; p[2] = v0.z; p[3] = v0.w;
        p[4] = v1.x; p[5] = v1.y; p[6] = v1.z; p[7] = v1.w;
        float4 w = *(const float4*)(W1 + (size_t)wk * DH + wc);
        float* q = &wl[0][wk * 64 + wc];
        q[0] = w.x; q[1] = w.y; q[2] = w.z; q[3] = w.w;
    }
    __syncthreads();
    for (int c = 0; c < 8; ++c) {
        const int buf = c & 1;
        if (c + 1 < 8) {   // stage next chunk into other buffer
            float4 v0 = *(const float4*)(x + xrow + (c + 1) * 32 + sk);
            float4 v1 = *(const float4*)(x + xrow + (c + 1) * 32 + sk + 4);
            float* p = &xs[buf ^ 1][sr * 33 + sk];
            p[0] = v0.x; p[1] = v0.y; p[2] = v0.z; p[3] = v0.w;
            p[4] = v1.x; p[5] = v1.y; p[6] = v1.z; p[7] = v1.w;
            float4 w = *(const float4*)(W1 + (size_t)((c + 1) * 32 + wk) * DH + wc);
            float* q = &wl[buf ^ 1][wk * 64 + wc];
            q[0] = w.x; q[1] = w.y; q[2] = w.z; q[3] = w.w;
        }
        #pragma unroll 4
        for (int kk = 0; kk < 32; ++kk) {
            float xa = xs[buf][lane * 33 + kk];
            float xb = xs[buf][(lane + 64) * 33 + kk];
            const float4* wp = (const float4*)&wl[buf][kk * 64 + wvu * 8];
            float4 wa = wp[0], wb = wp[1];
            accA[0] += wa.x * xa; accA[1] += wa.y * xa;
            accA[2] += wa.z * xa; accA[3] += wa.w * xa;
            accA[4] += wb.x * xa; accA[5] += wb.y * xa;
            accA[6] += wb.z * xa; accA[7] += wb.w * xa;
            accB[0] += wa.x * xb; accB[1] += wa.y * xb;
            accB[2] += wa.z * xb; accB[3] += wa.w * xb;
            accB[4] += wb.x * xb; accB[5] += wb.y * xb;
            accB[6] += wb.z * xb; accB[7] += wb.w * xb;
        }
        __syncthreads();
    }
    if (rowA < NN) {
        float di = dinv[rowA];
        float4 o0 = {di * accA[0], di * accA[1], di * accA[2], di * accA[3]};
        float4 o1 = {di * accA[4], di * accA[5], di * accA[6], di * accA[7]};
        float4* hp = (float4*)(h1s + (long)rowA * DH + wvu * 8);
        hp[0] = o0;
        hp[1] = o1;
    }
    if (rowB < NN) {
        float di = dinv[rowB];
        float4 o0 = {di * accB[0], di * accB[1], di * accB[2], di * accB[3]};
        float4 o1 = {di * accB[4], di * accB[5], di * accB[6], di * accB[7]};
        float4* hp = (float4*)(h1s + (long)rowB * DH + wvu * 8);
        hp[0] = o0;
        hp[1] = o1;
    }
}

// ---------------- layer1 gather (2 rows/wave) + relu/bias + GEMM2 fused ----------------
__global__ __launch_bounds__(256) void k_agg1(const int* __restrict__ rowptr,
                                              const int* __restrict__ deg,
                                              const int* __restrict__ csr_src,
                                              const float* __restrict__ dinv,
                                              const float* __restrict__ h1s,
                                              const float* __restrict__ b1,
                                              const float* __restrict__ W2,
                                              float* __restrict__ h3s) {
    __shared__ float w2[DH * DO];   // 12 KB
    __shared__ float sh[8][DH];     // 2 KB
    for (int i = threadIdx.x; i < DH * DO; i += 256) w2[i] = W2[i];
    __syncthreads();
    const int wv = threadIdx.x >> 6, lane = threadIdx.x & 63;
    const int rA = blockIdx.x * 8 + wv * 2;
    const int rB = rA + 1;
    const int begA = rowptr[rA], cntA = deg[rA];
    const int begB = rowptr[rB], cntB = deg[rB];
    float accA = 0.f, accB = 0.f;
    const int tmax = max(cntA, cntB);
    #pragma unroll 2
    for (int j = 0; j < tmax; j += 4) {
        #pragma unroll
        for (int k = 0; k < 4; ++k) {
            int sa = csr_src[min(begA + j + k, NE - 1)];
            int sb = csr_src[min(begB + j + k, NE - 1)];
            float va = h1s[(size_t)sa * DH + lane];
            float vb = h1s[(size_t)sb * DH + lane];
            accA += (j + k < cntA) ? va : 0.f;
            accB += (j + k < cntB) ? vb : 0.f;
        }
    }
    const float diA = dinv[rA], diB = dinv[rB];
    float vA = diA * (accA + h1s[(size_t)rA * DH + lane]) + b1[lane];
    float vB = diB * (accB + h1s[(size_t)rB * DH + lane]) + b1[lane];
    sh[wv * 2 + 0][lane] = fmaxf(vA, 0.f);
    sh[wv * 2 + 1][lane] = fmaxf(vB, 0.f);
    __syncthreads();
    if (lane < DO) {
        float oA = 0.f, oB = 0.f;
        #pragma unroll 8
        for (int k = 0; k < DH; ++k) {
            float w = w2[k * DO + lane];
            oA += sh[wv * 2 + 0][k] * w;
            oB += sh[wv * 2 + 1][k] * w;
        }
        h3s[(size_t)rA * DH3 + lane] = diA * oA;
        h3s[(size_t)rB * DH3 + lane] = diB * oB;
    }
}

// ---------------- layer2 gather (2 rows/wave) + softmax/argmax fused ----------------
__global__ __launch_bounds__(256) void k_agg2(const int* __restrict__ rowptr,
                                              const int* __restrict__ deg,
                                              const int* __restrict__ csr_src,
                                              const float* __restrict__ dinv,
                                              const float* __restrict__ h3s,
                                              const float* __restrict__ b2,
                                              float* __restrict__ logits,
                                              float* __restrict__ preds,
                                              float* __restrict__ xo) {
    const int wv = threadIdx.x >> 6, lane = threadIdx.x & 63;
    const int rA = blockIdx.x * 8 + wv * 2;
    const int rB = rA + 1;
    const int begA = rowptr[rA], cntA = deg[rA];
    const int begB = rowptr[rB], cntB = deg[rB];
    const bool act = lane < DO;
    const int lx = act ? lane : 0;
    float accA = 0.f, accB = 0.f;
    const int tmax = max(cntA, cntB);
    #pragma unroll 2
    for (int j = 0; j < tmax; j += 4) {
        #pragma unroll
        for (int k = 0; k < 4; ++k) {
            int sa = csr_src[min(begA + j + k, NE - 1)];
            int sb = csr_src[min(begB + j + k, NE - 1)];
            float va = h3s[(size_t)sa * DH3 + lx];
            float vb = h3s[(size_t)sb * DH3 + lx];
            accA += (j + k < cntA) ? va : 0.f;
            accB += (j + k < cntB) ? vb : 0.f;
        }
    }
    const float diA = dinv[rA], diB = dinv[rB];
    float valA = -INFINITY, valB = -INFINITY;
    if (act) {
        valA = diA * (accA + h3s[(size_t)rA * DH3 + lane]) + b2[lane];
        valB = diB * (accB + h3s[(size_t)rB * DH3 + lane]) + b2[lane];
        xo[(size_t)rA * DO + lane] = valA;
        xo[(size_t)rB * DO + lane] = valB;
    }
    float mA = valA, mB = valB;
    for (int off = 32; off; off >>= 1) {
        mA = fmaxf(mA, __shfl_xor(mA, off));
        mB = fmaxf(mB, __shfl_xor(mB, off));
    }
    int idxA = (act && valA == mA) ? lane : (1 << 30);
    int idxB = (act && valB == mB) ? lane : (1 << 30);
    for (int off = 32; off; off >>= 1) {
        idxA = min(idxA, __shfl_xor(idxA, off));
        idxB = min(idxB, __shfl_xor(idxB, off));
    }
    float evA = act ? expf(valA - mA) : 0.f;
    float evB = act ? expf(valB - mB) : 0.f;
    float sA = evA, sB = evB;
    for (int off = 32; off; off >>= 1) {
        sA += __shfl_xor(sA, off);
        sB += __shfl_xor(sB, off);
    }
    if (act) {
        logits[(size_t)rA * DO + lane] = evA / sA;
        logits[(size_t)rB * DO + lane] = evB / sB;
    }
    if (lane == 0) {
        preds[rA] = (float)idxA;
        preds[rB] = (float)idxB;
    }
}

extern "C" void kernel_launch(void* const* d_in, const int* in_sizes, int n_in,
                              void* d_out, int out_size, void* d_ws, size_t ws_size,
                              hipStream_t stream) {
    const float* x  = (const float*)d_in[0];
    const int*   ei = (const int*)d_in[1];
    const float* W1 = (const float*)d_in[2];
    const float* b1 = (const float*)d_in[3];
    const float* W2 = (const float*)d_in[4];
    const float* b2 = (const float*)d_in[5];
    const int* src = ei;          // edge_index[0]
    const int* dst = ei + NE;     // edge_index[1]

    float* out    = (float*)d_out;
    float* logits = out;                      // [N,47]
    float* preds  = out + (size_t)NN * DO;    // [N]
    float* xo     = preds + NN;               // [N,47]

    // workspace layout (~53 MB)
    char* wsb = (char*)d_ws;
    int*   deg     = (int*)wsb;                         wsb += (size_t)NN * 4;
    float* dinv    = (float*)wsb;                       wsb += (size_t)NN * 4;
    int*   rowptr  = (int*)wsb;                         wsb += (size_t)NN * 4;
    int*   cursor  = (int*)wsb;                         wsb += (size_t)NN * 4;
    int*   part    = (int*)wsb;                         wsb += (size_t)512 * 4;
    int*   csr_src = (int*)wsb;                         wsb += (size_t)NE * 4;
    float* h1s     = (float*)wsb;                       wsb += (size_t)NN * DH * 4;
    float* h3s     = (float*)wsb;                       wsb += (size_t)NN * DH3 * 4;

    hipMemsetAsync(deg, 0, NN * sizeof(int), stream);

    k_degree<<<8 * CPB, 256, 0, stream>>>(dst, deg);
    k_part<<<NB, 256, 0, stream>>>(deg, part);
    k_scanpart<<<1, 512, 0, stream>>>(part);
    k_scan3<<<NB, 256, 0, stream>>>(deg, part, rowptr, cursor, dinv);
    k_fillr<<<8 * CPB, 256, 0, stream>>>(src, dst, cursor, csr_src);
    k_gemm1<<<(NN + 127) / 128, 512, 0, stream>>>(x, W1, dinv, h1s);
    k_agg1<<<NN / 8, 256, 0, stream>>>(rowptr, deg, csr_src, dinv, h1s, b1, W2, h3s);
    k_agg2<<<NN / 8, 256, 0, stream>>>(rowptr, deg, csr_src, dinv, h3s, b2, logits, preds, xo);
}